// Round 6
// baseline (495.482 us; speedup 1.0000x reference)
//
#include <hip/hip_runtime.h>
#include <hip/hip_bf16.h>

// CapsModel: B=64 N=32 H=W=16 A=16 K=3 stride=2 -> Ho=Wo=7, M=32, SD=4, D=16
// conv routing: 2 sites/block, 512 thr (site x 8 nkl-groups x 32 m-lanes),
//               ONE site per thread -> 64 persistent floats.
//               launch_bounds(512,2) => 128 VGPR: NO SPILLS (R5's (512,4)
//               forced 64 VGPR and spilled 56 MB to scratch).
// fc routing:   pass-split kernels: partial (512 blocks) + combine/LN (64).
// No-max softmax (|logit| <~16, exp safe in fp32).

#define LN_EPS 1e-5f

// ---------------- weight transposes ----------------
// wT [288][32][16]: row r = n*9+kl (n-major, matches s_inp), wT[(r*32+m)*16+xd]
__global__ __launch_bounds__(256) void transpose_wconv(
    const float* __restrict__ wconv, float* __restrict__ wT)
{
    const int i = blockIdx.x * 256 + threadIdx.x;
    if (i < 147456) {
        const int xd = i & 15, mm = (i >> 4) & 31, r = i >> 9;   // r = n*9+kl
        const int n = r / 9, kl = r % 9;
        wT[i] = wconv[((kl * 32 + n) * 16 + xd) * 32 + mm];
    }
}

// wT2b [1568][16][16]: [n][m (pad 10->16, zeros)][x*4+d]
__global__ __launch_bounds__(256) void transpose_wfc(
    const float* __restrict__ wfc, float* __restrict__ wT2b)
{
    const int j = blockIdx.x * 256 + threadIdx.x;
    if (j < 401408) {
        const int xd = j & 15, mm = (j >> 4) & 15, n = j >> 8;
        const int x = xd >> 2, dd = xd & 3;
        wT2b[j] = (mm < 10) ? wfc[((n * 4 + x) * 4 + dd) * 10 + mm] : 0.f;
    }
}

// ---------------- Stage 1: conv routing ----------------
__global__ __launch_bounds__(512, 2) void conv_routing_kernel(
    const float* __restrict__ x,      // [64][32][16][16][16]
    const float* __restrict__ wT,     // [288][32][16], row = n*9+kl
    const float* __restrict__ ln1g,
    const float* __restrict__ ln1b,
    const int*   __restrict__ nroute,
    float* __restrict__ vout)         // [64][32][49][16]
{
    __shared__ float s_inp[2][288][16];     // 36 KB
    __shared__ float s_v[2][32][16];        // 4 KB
    __shared__ float s_red[3][2][32][16];   // 12 KB (waves 1..3 of each site)

    const int tid    = threadIdx.x;
    const int site_l = tid >> 8;            // 0/1
    const int m      = tid & 31;
    const int g      = (tid >> 5) & 7;      // 0..7
    const int lw     = (tid >> 6) & 3;      // wave within site
    const int hmask  = tid & 32;
    const int site0  = blockIdx.x * 2;

    // stage inp for both sites (float4, coalesced); row = n*9+kl
    for (int i = tid; i < 2304; i += 512) {
        const int s = (i >= 1152) ? 1 : 0;
        const int j = s ? i - 1152 : i;
        const int row = j >> 2, q = j & 3;
        const int site = site0 + s;
        const int b = site / 49, hw = site % 49;
        const int h = hw / 7, w = hw % 7;
        const int n = row / 9, kl = row % 9;
        const int k = kl / 3, l = kl % 3;
        const float4 val = *(const float4*)(
            x + ((((b * 32 + n) * 16 + (2 * h + k)) * 16 + (2 * w + l)) * 16 + q * 4));
        *(float4*)(&s_inp[s][row][q * 4]) = val;
    }
    __syncthreads();

    const int R = *nroute;
    const int nkl0 = g * 36;
    const float* const wp0 = wT + (nkl0 * 32 + m) * 16;

#define LDW(dst, p)                                                    \
    {                                                                  \
        _Pragma("unroll") for (int q = 0; q < 4; ++q)                  \
            *(float4*)(&(dst)[q * 4]) = *(const float4*)((p) + q * 4); \
    }

    for (int pass = 0; pass < R; ++pass) {
        float vn[16];
#pragma unroll
        for (int i = 0; i < 16; ++i) vn[i] = 0.f;
        float vc[16];
        if (pass) {
#pragma unroll
            for (int q = 0; q < 4; ++q)
                *(float4*)(&vc[q * 4]) = *(const float4*)(&s_v[site_l][m][q * 4]);
        }

        auto body0 = [&](int t, const float* wv) {
            const int nkl = nkl0 + t;
            float in_[16];
#pragma unroll
            for (int q = 0; q < 4; ++q)
                *(float4*)(&in_[q * 4]) = *(const float4*)(&s_inp[site_l][nkl][q * 4]);
#pragma unroll
            for (int a = 0; a < 4; ++a) {
#pragma unroll
                for (int d = 0; d < 4; ++d) {
                    float acc = in_[a * 4 + 0] * wv[0 + d];
                    acc = fmaf(in_[a * 4 + 1], wv[4 + d], acc);
                    acc = fmaf(in_[a * 4 + 2], wv[8 + d], acc);
                    acc = fmaf(in_[a * 4 + 3], wv[12 + d], acc);
                    vn[a * 4 + d] += acc;
                }
            }
        };

        auto body1 = [&](int t, const float* wv) {
            const int nkl = nkl0 + t;
            float in_[16];
#pragma unroll
            for (int q = 0; q < 4; ++q)
                *(float4*)(&in_[q * 4]) = *(const float4*)(&s_inp[site_l][nkl][q * 4]);
            float uh[16];
#pragma unroll
            for (int a = 0; a < 4; ++a) {
#pragma unroll
                for (int d = 0; d < 4; ++d) {
                    float acc = in_[a * 4 + 0] * wv[0 + d];
                    acc = fmaf(in_[a * 4 + 1], wv[4 + d], acc);
                    acc = fmaf(in_[a * 4 + 2], wv[8 + d], acc);
                    acc = fmaf(in_[a * 4 + 3], wv[12 + d], acc);
                    uh[a * 4 + d] = acc;
                }
            }
            float lg = 0.f;
#pragma unroll
            for (int i = 0; i < 16; ++i) lg = fmaf(uh[i], vc[i], lg);
            lg *= 0.25f;
            const float e = __expf(lg);
            float sm = e;
#pragma unroll
            for (int off = 16; off >= 1; off >>= 1)
                sm += __shfl_xor(sm, off, 32);
            const float qk = e * __builtin_amdgcn_rcpf(sm * (1.f + 1e-10f));
#pragma unroll
            for (int i = 0; i < 16; ++i) vn[i] = fmaf(qk, uh[i], vn[i]);
        };

        // K-loop, unroll 2 with double-buffered w prefetch
        {
            const float* wp = wp0;
            float wA[16], wB[16];
            LDW(wA, wp);
            if (pass == 0) {
                for (int t2 = 0; t2 < 18; ++t2) {
                    const int t = t2 * 2;
                    LDW(wB, wp + 512);
                    body0(t, wA);
                    if (t2 < 17) LDW(wA, wp + 1024);
                    body0(t + 1, wB);
                    wp += 1024;
                }
            } else {
                for (int t2 = 0; t2 < 18; ++t2) {
                    const int t = t2 * 2;
                    LDW(wB, wp + 512);
                    body1(t, wA);
                    if (t2 < 17) LDW(wA, wp + 1024);
                    body1(t + 1, wB);
                    wp += 1024;
                }
            }
        }

        // combine the 2 g's within each wave (both halves end with the pair-sum)
#pragma unroll
        for (int i = 0; i < 16; ++i) vn[i] += __shfl_xor(vn[i], 32, 64);

        if (lw > 0 && hmask == 0) {
#pragma unroll
            for (int q = 0; q < 4; ++q)
                *(float4*)(&s_red[lw - 1][site_l][m][q * 4]) = *(float4*)(&vn[q * 4]);
        }
        __syncthreads();

        if (lw == 0 && hmask == 0) {
#pragma unroll
            for (int j = 0; j < 3; ++j)
#pragma unroll
                for (int i = 0; i < 16; ++i) vn[i] += s_red[j][site_l][m][i];

            const float scale = pass ? 1.f : (1.f / 32.f);
            float mu = 0.f;
#pragma unroll
            for (int i = 0; i < 16; ++i) { vn[i] *= scale; mu += vn[i]; }
            mu *= (1.f / 16.f);
            float var = 0.f;
#pragma unroll
            for (int i = 0; i < 16; ++i) {
                const float d0 = vn[i] - mu;
                var = fmaf(d0, d0, var);
            }
            var *= (1.f / 16.f);
            const float inv = rsqrtf(var + LN_EPS);
#pragma unroll
            for (int i = 0; i < 16; ++i)
                s_v[site_l][m][i] = (vn[i] - mu) * inv * ln1g[i] + ln1b[i];
        }
        __syncthreads();
    }

    // write v: 256 float4
    if (tid < 256) {
        const int p = tid;
        const int s = p >> 7, mm = (p >> 2) & 31, q = p & 3;
        const int site = site0 + s;
        const int b = site / 49, hw = site % 49;
        const float4 val = *(const float4*)(&s_v[s][mm][q * 4]);
        *(float4*)(vout + ((b * 32 + mm) * 49 + hw) * 16 + q * 4) = val;
    }
}

// ---------------- Stage 2: FC routing (pass-split) ----------------
// fc_partial: 512 blocks = 64 b x 8 chunks; 256 thr = 16 grp x 16 ml.
// Chunk c covers n in [c*196, (c+1)*196); within it n = base + t*16 + grp.
__global__ __launch_bounds__(256, 4) void fc_partial(
    const float* __restrict__ fcin,  // [64][1568][16]
    const float* __restrict__ wT2b,  // [1568][16][16] ([n][ml][x*4+d])
    const float* __restrict__ u,     // [64][16][16] ([b][ml][ad])
    const int*   __restrict__ nroute,
    const int    pass,
    float* __restrict__ partial)     // [512][16][16]
{
    __shared__ float s_red[4][16][17];

    const int R = *nroute;
    if (pass >= R) return;
    const int blk = blockIdx.x;
    const int b = blk >> 3, c = blk & 7;
    const int tid = threadIdx.x;
    const int ml = tid & 15, grp = tid >> 4;   // grp 0..15
    const int wv = tid >> 6;
    const float* fb = fcin + (b * 1568 + c * 196) * 16;
    const float* wb = wT2b + (c * 196 * 16) * 16;

    float un[16];
#pragma unroll
    for (int i = 0; i < 16; ++i) un[i] = 0.f;
    float ur[16];
    if (pass) {
#pragma unroll
        for (int q = 0; q < 4; ++q)
            *(float4*)(&ur[q * 4]) = *(const float4*)(u + (b * 16 + ml) * 16 + q * 4);
    }

    for (int t = 0; t < 13; ++t) {
        const int off = t * 16 + grp;
        if (off >= 196) break;   // uniform within each 16-lane cluster
        float iv[16], wv_[16];
        const float* ip = fb + off * 16;
        const float* wp = wb + (off * 16 + ml) * 16;
#pragma unroll
        for (int q = 0; q < 4; ++q) {
            *(float4*)(&iv[q * 4]) = *(const float4*)(ip + q * 4);
            *(float4*)(&wv_[q * 4]) = *(const float4*)(wp + q * 4);
        }
        float vote[16];
#pragma unroll
        for (int a = 0; a < 4; ++a) {
#pragma unroll
            for (int d = 0; d < 4; ++d) {
                float acc = iv[a * 4 + 0] * wv_[0 + d];
                acc = fmaf(iv[a * 4 + 1], wv_[4 + d], acc);
                acc = fmaf(iv[a * 4 + 2], wv_[8 + d], acc);
                acc = fmaf(iv[a * 4 + 3], wv_[12 + d], acc);
                vote[a * 4 + d] = acc;
            }
        }
        if (pass == 0) {
#pragma unroll
            for (int i = 0; i < 16; ++i) un[i] += vote[i];
        } else {
            float lg = 0.f;
#pragma unroll
            for (int i = 0; i < 16; ++i) lg = fmaf(vote[i], ur[i], lg);
            lg *= 0.25f;
            float e = __expf(lg);
            if (ml >= 10) e = 0.f;
            float sm = e;
#pragma unroll
            for (int off2 = 8; off2 >= 1; off2 >>= 1)
                sm += __shfl_xor(sm, off2, 16);
            const float qk = e * __builtin_amdgcn_rcpf(sm * (1.f + 1e-10f));
#pragma unroll
            for (int i = 0; i < 16; ++i) un[i] = fmaf(qk, vote[i], un[i]);
        }
    }

    // sum the 4 grps within each wave
#pragma unroll
    for (int i = 0; i < 16; ++i) {
        un[i] += __shfl_xor(un[i], 16, 64);
        un[i] += __shfl_xor(un[i], 32, 64);
    }
    if ((tid & 63) < 16) {
#pragma unroll
        for (int i = 0; i < 16; ++i) s_red[wv][ml][i] = un[i];
    }
    __syncthreads();

    // 256 threads: (mlf, i) -> sum 4 waves, write partial
    {
        const int mlf = tid >> 4, i = tid & 15;
        const float s = s_red[0][mlf][i] + s_red[1][mlf][i]
                      + s_red[2][mlf][i] + s_red[3][mlf][i];
        partial[(blk * 16 + mlf) * 16 + i] = s;
    }
}

// fc_combine: 64 blocks x 256 thr; thread = (ml = tid>>4, i = tid&15).
__global__ __launch_bounds__(256) void fc_combine(
    const float* __restrict__ partial,  // [512][16][16]
    const float* __restrict__ ln2g,
    const float* __restrict__ ln2b,
    const int*   __restrict__ nroute,
    const int    pass,
    float* __restrict__ u,              // [64][16][16]
    float* __restrict__ out)            // [64][10][16]
{
    const int R = *nroute;
    if (pass >= R) return;
    const int b = blockIdx.x;
    const int tid = threadIdx.x;
    const int i = tid & 15, ml = tid >> 4;

    float s = 0.f;
#pragma unroll
    for (int c = 0; c < 8; ++c)
        s += partial[((b * 8 + c) * 16 + ml) * 16 + i];
    if (pass == 0) s *= 0.1f;

    // LN over the 16 i-lanes of this cluster
    float mu = s;
#pragma unroll
    for (int off = 8; off >= 1; off >>= 1) mu += __shfl_xor(mu, off, 16);
    mu *= (1.f / 16.f);
    const float d0 = s - mu;
    float var = d0 * d0;
#pragma unroll
    for (int off = 8; off >= 1; off >>= 1) var += __shfl_xor(var, off, 16);
    var *= (1.f / 16.f);
    const float r = (s - mu) * rsqrtf(var + LN_EPS) * ln2g[i] + ln2b[i];

    u[(b * 16 + ml) * 16 + i] = r;
    if (pass == R - 1 && ml < 10) out[(b * 10 + ml) * 16 + i] = r;
}

extern "C" void kernel_launch(void* const* d_in, const int* in_sizes, int n_in,
                              void* d_out, int out_size, void* d_ws, size_t ws_size,
                              hipStream_t stream) {
    const float* x     = (const float*)d_in[0];
    const float* wconv = (const float*)d_in[1];
    const float* wfc   = (const float*)d_in[2];
    const float* ln1g  = (const float*)d_in[3];
    const float* ln1b  = (const float*)d_in[4];
    const float* ln2g  = (const float*)d_in[5];
    const float* ln2b  = (const float*)d_in[6];
    const int*   nrt   = (const int*)d_in[7];

    float* vout    = (float*)d_ws;                               // 6,422,528 B
    // wT (589,824 B) and wT2b (1,605,632 B) share this region (sequenced).
    float* wT      = (float*)((char*)d_ws + 6422528);
    float* wT2b    = (float*)((char*)d_ws + 6422528);
    float* ubuf    = (float*)((char*)d_ws + 8028160);            // 65,536 B
    float* partial = (float*)((char*)d_ws + 8093696);            // 524,288 B
    float* out     = (float*)d_out;

    hipLaunchKernelGGL(transpose_wconv, dim3(576), dim3(256), 0, stream,
                       wconv, wT);
    hipLaunchKernelGGL(conv_routing_kernel, dim3(1568), dim3(512), 0, stream,
                       x, wT, ln1g, ln1b, nrt, vout);
    hipLaunchKernelGGL(transpose_wfc, dim3(1568), dim3(256), 0, stream,
                       wfc, wT2b);
    for (int pass = 0; pass < 3; ++pass) {
        hipLaunchKernelGGL(fc_partial, dim3(512), dim3(256), 0, stream,
                           vout, wT2b, ubuf, nrt, pass, partial);
        hipLaunchKernelGGL(fc_combine, dim3(64), dim3(256), 0, stream,
                           partial, ln2g, ln2b, nrt, pass, ubuf, out);
    }
}